// Round 3
// baseline (278.151 us; speedup 1.0000x reference)
//
#include <hip/hip_runtime.h>
#include <stdint.h>

// DCT2D: y = Dh @ x @ Dw^T per (b,c); B=32,H=W=512,C=3, fp32 in/out.
// bf16 MFMA (16x16x32), two GEMM passes via bf16 intermediate Y[b,k,c,w].
// R2: counted s_waitcnt vmcnt(N) + raw s_barrier (T4) so prefetches stay in
// flight ACROSS barriers (R1's __syncthreads drained them -> no overlap).
// R3: fix pass2 vmcnt off-by-one (stage = 4 ops for t<128 / 3 ops for t>=128;
// must wait to vmcnt(4)/vmcnt(3), not 5/4 -- Bs1 was crossing the barrier
// unretired -> uninitialized LDS -> NaN).

typedef __bf16 bf16_t;
typedef bf16_t bf16x8 __attribute__((ext_vector_type(8)));
typedef float  f32x4  __attribute__((ext_vector_type(4)));

#define SCHED0 __builtin_amdgcn_sched_barrier(0)
#define SBAR   __builtin_amdgcn_s_barrier()
#define LGKM0  asm volatile("s_waitcnt lgkmcnt(0)" ::: "memory")
#define VMW(n) asm volatile("s_waitcnt vmcnt(" #n ")" ::: "memory")

__device__ __forceinline__ uint32_t f2bf(float f) {
    union { float f; uint32_t u; } v; v.f = f;
    uint32_t r = v.u + 0x7fffu + ((v.u >> 16) & 1u);   // RNE
    return r >> 16;
}

__device__ __forceinline__ f32x4 mfma16(bf16x8 a, bf16x8 b, f32x4 c) {
    return __builtin_amdgcn_mfma_f32_16x16x32_bf16(a, b, c, 0, 0, 0);
}

__device__ __forceinline__ void load_lds16(const void* g, void* l) {
    __builtin_amdgcn_global_load_lds(
        (const __attribute__((address_space(1))) uint32_t*)g,
        (__attribute__((address_space(3))) uint32_t*)l, 16, 0, 0);
}

// ---------------- D matrix generation (bf16, row-major D[k][h]) -------------
__global__ __launch_bounds__(256) void gen_dct(uint16_t* __restrict__ Dbf) {
    int idx = blockIdx.x * 256 + threadIdx.x;      // 512*512 elems
    int k = idx >> 9, h = idx & 511;
    int phase = ((2 * h + 1) * k) & 2047;          // exact mod-2048 reduction
    float ang = (float)phase * 3.0679615757712823e-3f;   // pi/1024
    float s = (k == 0) ? 0.04419417382415922f : 0.0625f; // sqrt(1/512), sqrt(2/512)
    Dbf[idx] = (uint16_t)f2bf(__cosf(ang) * s);
}

// ---------------- Pass 1: Y[b,k,c,w] = sum_h D[k,h] * x[b,h,w,c] ------------
// GEMM per b: C[m=k(128-tile), n=remapped (c,w) col (96-tile)], K=h, BK=32.
// Pipeline per iter k: issueA(k+1) | issueX(k+2)->regs | packB(k+1) |
// MFMA(k) | lgkmcnt(0); vmcnt(16) [retires A(k+1), leaves X(k+2)]; s_barrier.
__global__ __launch_bounds__(256, 4) void pass1(const float* __restrict__ x,
                                                const uint16_t* __restrict__ Dbf,
                                                uint16_t* __restrict__ Y) {
    __shared__ __align__(16) uint16_t Alds[2][128 * 32];   // 16 KB
    __shared__ __align__(16) uint16_t Blds[2][96 * 32];    // 12 KB
    const int t = threadIdx.x;
    const int lane = t & 63, wv = t >> 6;
    const int nt = blockIdx.x;   // j-tile 0..15 (96 cols = 32 w * 3 c)
    const int mt = blockIdx.y;   // k-tile 0..3
    const int b  = blockIdx.z;
    const float* xb = x + (size_t)b * (512 * 1536);

    // A staging: slot q -> row m=q>>2, slot i=q&3 holds global chunk i^((m>>1)&3)
    const int q0 = t, q1 = t + 256;
    const int m0 = q0 >> 2, i0 = (q0 & 3) ^ ((m0 >> 1) & 3);
    const int m1 = q1 >> 2, i1 = (q1 & 3) ^ ((m1 >> 1) & 3);
    const uint16_t* Asrc0 = Dbf + (size_t)(mt * 128 + m0) * 512 + i0 * 8;
    const uint16_t* Asrc1 = Dbf + (size_t)(mt * 128 + m1) * 512 + i1 * 8;

    // B-staging mapping (threads 0..191): jl -> (w,c); col remap so that
    // MFMA col-tiles 2c/2c+1 hold even/odd w (paired bf16 stores).
    const int jl = t % 96;
    const int hh = t / 96;                       // 0/1 -> h-halves of 16
    const int wl = jl / 3, cc = jl - 3 * wl;
    const int ncol = cc * 32 + ((wl >> 1) + ((wl & 1) << 4));
    const int xv = ((ncol >> 1) ^ (ncol >> 3) ^ (ncol >> 5)) & 3;  // 16B chunk XOR
    const int jg = nt * 96 + jl;
    const float* xsrc = xb + (size_t)(hh * 16) * 1536 + jg;

    f32x4 acc[2][6] = {};
    float vx0[16], vx1[16];       // two static X register banks (rule #20)

    auto issueA = [&](int kk) {
        load_lds16(Asrc0 + kk * 32, &Alds[kk & 1][q0 * 8]);
        load_lds16(Asrc1 + kk * 32, &Alds[kk & 1][q1 * 8]);
    };
    auto issueX = [&](float (&vv)[16], int kk) {
        if (t < 192) {
            const float* s = xsrc + (size_t)kk * 32 * 1536;
#pragma unroll
            for (int r = 0; r < 16; ++r) vv[r] = s[(size_t)r * 1536];
        }
    };
    auto packB = [&](const float (&vv)[16], int kk) {
        if (t < 192) {
            uint32_t p[8];
#pragma unroll
            for (int i = 0; i < 8; ++i)
                p[i] = f2bf(vv[2 * i]) | (f2bf(vv[2 * i + 1]) << 16);
            uint16_t* B = Blds[kk & 1];
            *(uint4*)&B[ncol * 32 + (((hh * 2 + 0) ^ xv) << 3)] =
                make_uint4(p[0], p[1], p[2], p[3]);
            *(uint4*)&B[ncol * 32 + (((hh * 2 + 1) ^ xv) << 3)] =
                make_uint4(p[4], p[5], p[6], p[7]);
        }
    };
    auto compute = [&](int kk) {
        const uint16_t* A  = Alds[kk & 1];
        const uint16_t* Bl = Blds[kk & 1];
        bf16x8 aq[2];
#pragma unroll
        for (int i = 0; i < 2; ++i) {
            int row = (wv * 2 + i) * 16 + (lane & 15);
            aq[i] = *(const bf16x8*)&A[row * 32 +
                        (((lane >> 4) ^ ((row >> 1) & 3)) << 3)];
        }
#pragma unroll
        for (int tt = 0; tt < 6; ++tt) {
            int col = tt * 16 + (lane & 15);
            int xr = ((col >> 1) ^ (col >> 3) ^ (col >> 5)) & 3;
            bf16x8 bq = *(const bf16x8*)&Bl[col * 32 + (((lane >> 4) ^ xr) << 3)];
            acc[0][tt] = mfma16(aq[0], bq, acc[0][tt]);
            acc[1][tt] = mfma16(aq[1], bq, acc[1][tt]);
        }
    };
    auto endstep = [&](int kt) {
        LGKM0;                                    // B ds_writes visible
        if (kt <= 13 && t < 192) { VMW(16); }     // retire A(kt+1), leave X(kt+2)
        else                     { VMW(0);  }     // wave3 / tail: drain
        SBAR; SCHED0;
    };

    // ---- prologue: X(0), A(0), X(1); pack B(0); wait A(0); barrier ----
    issueX(vx0, 0); SCHED0;
    issueA(0);      SCHED0;
    issueX(vx1, 1); SCHED0;
    packB(vx0, 0);
    endstep(0);

    for (int k2 = 0; k2 < 8; ++k2) {
        const int ke = 2 * k2, ko = ke + 1;
        // ---- even iter ke: banks X->vx0, pack vx1 ----
        issueA(ko);                      SCHED0;
        if (ke + 2 < 16) issueX(vx0, ke + 2);
        SCHED0;
        packB(vx1, ko);
        compute(ke);
        endstep(ke);
        // ---- odd iter ko: banks X->vx1, pack vx0 ----
        if (ko + 1 < 16) issueA(ko + 1);
        SCHED0;
        if (ko + 2 < 16) issueX(vx1, ko + 2);
        SCHED0;
        if (ko + 1 < 16) packB(vx0, ko + 1);
        compute(ko);
        if (ko < 15) endstep(ko);
    }

    // Epilogue: direct coalesced dword stores (bf16 pair at adjacent w).
    const int wg = nt * 32 + 2 * (lane & 15);
#pragma unroll
    for (int i = 0; i < 2; ++i) {
        int kg = mt * 128 + (wv * 2 + i) * 16 + ((lane >> 4) << 2);
#pragma unroll
        for (int c = 0; c < 3; ++c)
#pragma unroll
            for (int r = 0; r < 4; ++r) {
                uint32_t pk = f2bf(acc[i][2 * c][r]) | (f2bf(acc[i][2 * c + 1][r]) << 16);
                *(uint32_t*)&Y[(size_t)b * 786432 + (size_t)(kg + r) * 1536 + c * 512 + wg] = pk;
            }
    }
}

// ---------------- Pass 2: out[b,k,l,c] = sum_w D[l,w] * Y[b,k,c,w] ----------
// GEMM per b: C[m=kc(96-tile), n=l(128-tile)], K=w, BK=32.
// Triple-buffered LDS; stage(k+2) issued in iter k, retired one barrier later.
// stage issues 4 VMEM ops for t<128 (As0,As1,Bs0,Bs1) and 3 for t>=128;
// retiring the OLDER stage => wait to vmcnt(4) / vmcnt(3) exactly.
__global__ __launch_bounds__(256, 3) void pass2(const uint16_t* __restrict__ Y,
                                                const uint16_t* __restrict__ Dbf,
                                                float* __restrict__ out) {
    __shared__ __align__(16) char smem[43008];   // 3 x (A 6144 + B 8192)
    const int t = threadIdx.x;
    const int lane = t & 63, wv = t >> 6;
    const int lt = blockIdx.x;   // l-tile 0..3
    const int mt = blockIdx.y;   // kc-tile 0..15
    const int b  = blockIdx.z;
    const size_t yb = (size_t)b * 786432;

    const int qa0 = t;
    const int ma0 = qa0 >> 2, ia0 = (qa0 & 3) ^ ((ma0 >> 1) & 3);
    const int qa1 = t + 256;
    const int ma1 = qa1 >> 2, ia1 = (qa1 & 3) ^ ((ma1 >> 1) & 3);

    const uint16_t* As0 = Y + yb + (size_t)(mt * 96 + ma0) * 512 + ia0 * 8;
    const uint16_t* As1 = Y + yb + (size_t)(mt * 96 + ma1) * 512 + ia1 * 8;  // rows 64..95 (t<128)
    const uint16_t* Bs0 = Dbf + (size_t)(lt * 128 + ma0) * 512 + ia0 * 8;    // rows 0..63
    const uint16_t* Bs1 = Dbf + (size_t)(lt * 128 + ma1) * 512 + ia1 * 8;    // rows 64..127

    f32x4 acc[6][2] = {};

    auto stage = [&](int kt, int buf) {
        uint16_t* Al = (uint16_t*)(smem + buf * 14336);
        uint16_t* Bl = (uint16_t*)(smem + buf * 14336 + 6144);
        load_lds16(As0 + kt * 32, Al + qa0 * 8);
        if (t < 128) load_lds16(As1 + kt * 32, Al + qa1 * 8);
        load_lds16(Bs0 + kt * 32, Bl + qa0 * 8);
        load_lds16(Bs1 + kt * 32, Bl + qa1 * 8);
    };
    auto compute = [&](int buf) {
        const uint16_t* Al = (const uint16_t*)(smem + buf * 14336);
        const uint16_t* Bl = (const uint16_t*)(smem + buf * 14336 + 6144);
        bf16x8 bq[2];
#pragma unroll
        for (int p = 0; p < 2; ++p) {
            int row = (wv * 2 + p) * 16 + (lane & 15);
            bq[p] = *(const bf16x8*)&Bl[row * 32 +
                        (((lane >> 4) ^ ((row >> 1) & 3)) << 3)];
        }
#pragma unroll
        for (int tt = 0; tt < 6; ++tt) {
            int row = tt * 16 + (lane & 15);
            bf16x8 aq = *(const bf16x8*)&Al[row * 32 +
                        (((lane >> 4) ^ ((row >> 1) & 3)) << 3)];
            acc[tt][0] = mfma16(aq, bq[0], acc[tt][0]);
            acc[tt][1] = mfma16(aq, bq[1], acc[tt][1]);
        }
    };

    // prologue: stage(0), stage(1); retire stage(0) exactly; barrier
    stage(0, 0); SCHED0;
    stage(1, 1); SCHED0;
    if (t < 128) { VMW(4); } else { VMW(3); }
    SBAR; SCHED0;

    for (int kt = 0; kt < 16; ++kt) {
        if (kt + 2 < 16) stage(kt + 2, (kt + 2) % 3);
        SCHED0;
        compute(kt % 3);
        if (kt < 15) {
            if (kt <= 13) { if (t < 128) { VMW(4); } else { VMW(3); } }
            else          { VMW(0); }
            SBAR; SCHED0;
        }
    }

    // Epilogue: transpose [kc][l] -> out rows [k][(l,c)] in two l-halves
    // via padded LDS (96 x 65 fp32 = 24.96 KB, fits the smem union).
    __syncthreads();
    float* El = (float*)smem;
    const int kloc = t >> 3, sub = t & 7;   // 32 k-rows, 8 threads per row
#pragma unroll
    for (int hf = 0; hf < 2; ++hf) {
        __syncthreads();
        if ((wv >> 1) == hf) {              // waves owning l in [hf*64, hf*64+64)
#pragma unroll
            for (int tt = 0; tt < 6; ++tt)
#pragma unroll
                for (int p = 0; p < 2; ++p) {
                    int m = tt * 16 + ((lane >> 4) << 2);
                    int lc = ((wv & 1) * 2 + p) * 16 + (lane & 15);  // local l
#pragma unroll
                    for (int r = 0; r < 4; ++r)
                        El[(m + r) * 65 + lc] = acc[tt][p][r];
                }
        }
        __syncthreads();
        size_t ob = (size_t)b * 786432 + (size_t)(mt * 32 + kloc) * 1536 +
                    lt * 384 + hf * 192 + sub * 24;
#pragma unroll
        for (int q = 0; q < 6; ++q) {
            int o0 = hf * 192 + sub * 24 + q * 4;
            float4 v;
            v.x = El[(kloc * 3 + ((o0 + 0) % 3)) * 65 + ((o0 + 0) / 3 - hf * 64)];
            v.y = El[(kloc * 3 + ((o0 + 1) % 3)) * 65 + ((o0 + 1) / 3 - hf * 64)];
            v.z = El[(kloc * 3 + ((o0 + 2) % 3)) * 65 + ((o0 + 2) / 3 - hf * 64)];
            v.w = El[(kloc * 3 + ((o0 + 3) % 3)) * 65 + ((o0 + 3) / 3 - hf * 64)];
            *(float4*)&out[ob + q * 4] = v;
        }
    }
}

// ---------------------------------------------------------------------------
extern "C" void kernel_launch(void* const* d_in, const int* in_sizes, int n_in,
                              void* d_out, int out_size, void* d_ws, size_t ws_size,
                              hipStream_t stream) {
    (void)in_sizes; (void)n_in; (void)out_size; (void)ws_size;
    const float* x = (const float*)d_in[0];
    float* out = (float*)d_out;
    uint16_t* Dbf = (uint16_t*)d_ws;                 // 512*512 bf16 = 512 KB
    uint16_t* Y   = (uint16_t*)d_ws + 512 * 512;     // 32*512*512*3 bf16 = 48 MB

    gen_dct<<<1024, 256, 0, stream>>>(Dbf);
    dim3 g1(16, 4, 32);
    pass1<<<g1, 256, 0, stream>>>(x, Dbf, Y);
    dim3 g2(4, 16, 32);
    pass2<<<g2, 256, 0, stream>>>(Y, Dbf, out);
}